// Round 5
// baseline (57.754 us; speedup 1.0000x reference)
//
#include <hip/hip_runtime.h>

// B=8, C=512, T=8192, RATIO=2, K=12
#define T_LEN 8192
#define C_N   512
#define BLOCK 256
#define OPT   8                       // outputs per thread
#define TCHUNK (BLOCK * OPT)          // 2048
#define NCHUNK 4
#define INV_2PI 0.15915494309189535f

// Verified formulas (ground truth = rounds 0-4, all passing):
//   y[2i]   = 2 * sum_t wup[2t+1] * xc[i+2-t]   (t=0..5, xc = edge-clamped x)
//   y[2i+1] = 2 * sum_t wup[2t]   * xc[i+3-t]
//   snake:   y += sin(a*y)^2 / (a+1e-9)
//   out[n]  = sum_k wdn[k] * ypad[2n-5+k]       (ypad = edge-clamped y)
//
// Mapping: lane handles outputs N..N+7.
//   own pairs i = N-3..N+4 -> yv[u] = y[2N-6+u], u=0..15
//   halo h[v] = y[2N+10+v], v=0..10  <- lane+1's yv[0..10] via shfl_down
//   WAVE boundary (lane 63): halo y's are computed IN PARALLEL by lanes
//   0..10 (one y each, all-lanes execution, no serial exec-masked tail),
//   then gathered into lane 63 via readlane + cndmask.
//     lane v = 2s+par computes yh = y[2(N63+5+s)+par]
//       even (par=0): yh = sum_t u2[2t+1]*xc[N63+7+s-t] = sum_j u2[11-2j]*xt[j]
//       odd  (par=1): yh = sum_t u2[2t]  *xc[N63+8+s-t] = sum_j u2[10-2j]*xt[j]
//       with xt[j] = xc[N63+2+s+par+j], j=0..5

__global__ __launch_bounds__(BLOCK) void act1d_fused(
    const float* __restrict__ x,
    const float* __restrict__ alpha,
    const float* __restrict__ wup_g,
    const float* __restrict__ wdn_g,
    float* __restrict__ out)
{
    const int bx    = blockIdx.x;
    const int chunk = bx & (NCHUNK - 1);
    const int bc    = bx >> 2;              // row index b*C + c
    const int c     = bc & (C_N - 1);
    const int tid   = threadIdx.x;
    const int lane  = tid & 63;
    const int N     = chunk * TCHUNK + OPT * tid;   // first output of this lane
    const int N63   = N + OPT * (63 - lane);        // wave's lane-63 N (uniform)

    const float* __restrict__ xrow = x   + (size_t)bc * T_LEN;
    float*       __restrict__ orow = out + (size_t)bc * T_LEN;

    // ---- main x window: xr[u] = xc[N-8+u], u=0..15 (4x dwordx4) ----
    float xr[16];
    if (N >= 8) {
#pragma unroll
        for (int w = 0; w < 4; ++w) {
            const float4 t4 = *reinterpret_cast<const float4*>(xrow + N - 8 + 4 * w);
            xr[4 * w + 0] = t4.x;
            xr[4 * w + 1] = t4.y;
            xr[4 * w + 2] = t4.z;
            xr[4 * w + 3] = t4.w;
        }
    } else {   // only N==0: left edge clamp
#pragma unroll
        for (int u = 0; u < 16; ++u)
            xr[u] = xrow[max(N - 8 + u, 0)];
    }

    // ---- halo taps (issued early; lanes 0..10 meaningful, rest harmless) ----
    const int s_  = lane >> 1;
    const int par = lane & 1;
    const int hb  = N63 + 2 + s_ + par;
    float xt[6];
    if (N63 + 12 < T_LEN) {             // wave-uniform: all but last wave of row
#pragma unroll
        for (int j = 0; j < 6; ++j)
            xt[j] = xrow[hb + j];
    } else {
#pragma unroll
        for (int j = 0; j < 6; ++j)
            xt[j] = xrow[min(hb + j, T_LEN - 1)];
    }

    // ---- uniform constants ----
    float u2[12], wdn[12];
#pragma unroll
    for (int i = 0; i < 12; ++i) {
        u2[i]  = wup_g[i] + wup_g[i];   // fold the *2 of the transposed conv
        wdn[i] = wdn_g[i];
    }
    const float a     = __expf(alpha[c]);
    const float inv_a = 1.0f / (a + 1e-9f);
    const float ka    = a * INV_2PI;    // v_sin_f32 takes revolutions

    // ---- own 8 pairs: upsample ----
    float yv[16];
#pragma unroll
    for (int p = 0; p < 8; ++p) {
        float ae = 0.0f, ao = 0.0f;
#pragma unroll
        for (int t = 0; t < 6; ++t) {
            ae = fmaf(u2[2 * t + 1], xr[7 + p - t], ae);   // y[2(N-3+p)]
            ao = fmaf(u2[2 * t],     xr[8 + p - t], ao);   // y[2(N-3+p)+1]
        }
        yv[2 * p]     = ae;
        yv[2 * p + 1] = ao;
    }
    // ---- snake ----
#pragma unroll
    for (int q = 0; q < 16; ++q) {
        const float s = __builtin_amdgcn_sinf(ka * yv[q]);  // sin(a*y)
        yv[q] = fmaf(s * s, inv_a, yv[q]);
    }

    // ---- left edge: ypad[m<0] = y[0] (= yv[6] when N==0) ----
    if (N == 0) {
        yv[1] = yv[2] = yv[3] = yv[4] = yv[5] = yv[6];
    }

    // ---- parallel halo y (all lanes execute; lane v<11 is the real one) ----
    float yh = 0.0f;
#pragma unroll
    for (int j = 0; j < 6; ++j) {
        const float cj = par ? u2[10 - 2 * j] : u2[11 - 2 * j];
        yh = fmaf(cj, xt[j], yh);
    }
    {
        const float s = __builtin_amdgcn_sinf(ka * yh);
        yh = fmaf(s * s, inv_a, yh);
    }

    // ---- h[v]: lanes<63 take lane+1's yv[v]; lane 63 takes readlane(yh, v) ----
    const bool is63 = (lane == 63);
    float h[11];
#pragma unroll
    for (int v = 0; v < 11; ++v) {
        const float dwn = __shfl_down(yv[v], 1, 64);
        const float gat = __int_as_float(
            __builtin_amdgcn_readlane(__float_as_int(yh), v));
        h[v] = is63 ? gat : dwn;
    }

    // ---- right edge: ypad[m>16383] = y[16383] (= h[5] when N==T-8) ----
    if (N == T_LEN - OPT) {
        h[6] = h[7] = h[8] = h[9] = h[10] = h[5];
    }

    // ---- downsample: out[N+r] = sum_k wdn[k] * Y[2r+k] ----
    float o[OPT];
#pragma unroll
    for (int r = 0; r < OPT; ++r) {
        float acc = 0.0f;
#pragma unroll
        for (int k = 0; k < 12; ++k) {
            const int j = 2 * r + k;
            acc = fmaf(wdn[k], (j < 15 ? yv[j + 1] : h[j - 15]), acc);
        }
        o[r] = acc;
    }

    *reinterpret_cast<float4*>(orow + N)     = make_float4(o[0], o[1], o[2], o[3]);
    *reinterpret_cast<float4*>(orow + N + 4) = make_float4(o[4], o[5], o[6], o[7]);
}

extern "C" void kernel_launch(void* const* d_in, const int* in_sizes, int n_in,
                              void* d_out, int out_size, void* d_ws, size_t ws_size,
                              hipStream_t stream)
{
    const float* x     = (const float*)d_in[0];
    const float* alpha = (const float*)d_in[1];
    const float* wup   = (const float*)d_in[2];
    const float* wdn   = (const float*)d_in[3];
    float*       out   = (float*)d_out;

    const int B_N  = out_size / (C_N * T_LEN);   // 8
    const int grid = B_N * C_N * NCHUNK;         // 16384

    act1d_fused<<<grid, BLOCK, 0, stream>>>(x, alpha, wup, wdn, out);
}

// Round 6
// 48.533 us; speedup vs baseline: 1.1900x; 1.1900x over previous
//
#include <hip/hip_runtime.h>

// B=8, C=512, T=8192, RATIO=2, K=12
#define T_LEN 8192
#define C_N   512
#define BLOCK 256
#define OPT   8                       // outputs per thread
#define TCHUNK (BLOCK * OPT)          // 2048
#define NCHUNK 4
#define INV_2PI 0.15915494309189535f

typedef float f32x2 __attribute__((ext_vector_type(2)));

// Verified formulas (ground truth = rounds 0-5, all passing):
//   y[2i]   = 2 * sum_t wup[2t+1] * xc[i+2-t]   (t=0..5, xc = edge-clamped x)
//   y[2i+1] = 2 * sum_t wup[2t]   * xc[i+3-t]
//   snake:   y += sin(a*y)^2 / (a+1e-9)
//   out[n]  = sum_k wdn[k] * ypad[2n-5+k]       (ypad = edge-clamped y)
//
// Packed-f32 formulation (v_pk_fma_f32):
//   yv[u] = y[2N-6+u].  Pair A_p := (yv[2p], yv[2p-1]), p=1..8.
//   Both halves share tap xr[7+p-t]:
//     A_p = sum_t cpair[t] * splat(xr[7+p-t]),  cpair[t]=(u2[2t+1], u2[2t])
//   Downsample: out[N+r] = sum_j dpair[j] (.) A_{r+j+1}, summed over halves,
//     dpair[j] = (wdn[2j+1], wdn[2j]),  r=0..7, j=0..5  (uses A_1..A_13)
//   Halo pairs: A_{8+p} = shfl_down(A_p), p=1..5  (= (h[2p], h[2p-1]));
//     lane 63 gathers from the lane-parallel halo yh via readlane
//     (lane v=2s+par computes yh = y[2(N63+5+s)+par] from taps
//      xt[j]=xc[N63+2+s+par+j], coeff par ? u2[10-2j] : u2[11-2j]).

__global__ __launch_bounds__(BLOCK) void act1d_fused(
    const float* __restrict__ x,
    const float* __restrict__ alpha,
    const float* __restrict__ wup_g,
    const float* __restrict__ wdn_g,
    float* __restrict__ out)
{
    const int bx    = blockIdx.x;
    const int chunk = bx & (NCHUNK - 1);
    const int bc    = bx >> 2;              // row index b*C + c
    const int c     = bc & (C_N - 1);
    const int tid   = threadIdx.x;
    const int lane  = tid & 63;
    const int N     = chunk * TCHUNK + OPT * tid;   // first output of this lane
    const int N63   = N + OPT * (63 - lane);        // wave's lane-63 N (uniform)

    const float* __restrict__ xrow = x   + (size_t)bc * T_LEN;
    float*       __restrict__ orow = out + (size_t)bc * T_LEN;

    // ---- main x window: xr[u] = xc[N-8+u], u=0..15 (4x dwordx4) ----
    float xr[16];
    if (N >= 8) {
#pragma unroll
        for (int w = 0; w < 4; ++w) {
            const float4 t4 = *reinterpret_cast<const float4*>(xrow + N - 8 + 4 * w);
            xr[4 * w + 0] = t4.x;
            xr[4 * w + 1] = t4.y;
            xr[4 * w + 2] = t4.z;
            xr[4 * w + 3] = t4.w;
        }
    } else {   // only N==0: left edge clamp
#pragma unroll
        for (int u = 0; u < 16; ++u)
            xr[u] = xrow[max(N - 8 + u, 0)];
    }

    // ---- halo taps (issued early; lanes 0..10 meaningful, rest harmless) ----
    const int s_  = lane >> 1;
    const int par = lane & 1;
    const int hb  = N63 + 2 + s_ + par;
    float xt[6];
    if (N63 + 12 < T_LEN) {             // wave-uniform fast path
#pragma unroll
        for (int j = 0; j < 6; ++j)
            xt[j] = xrow[hb + j];
    } else {
#pragma unroll
        for (int j = 0; j < 6; ++j)
            xt[j] = xrow[min(hb + j, T_LEN - 1)];
    }

    // ---- uniform constants, packed ----
    f32x2 cpair[6], dpair[6];
#pragma unroll
    for (int t = 0; t < 6; ++t) {
        cpair[t] = (f32x2){ wup_g[2 * t + 1] + wup_g[2 * t + 1],
                            wup_g[2 * t]     + wup_g[2 * t] };
        dpair[t] = (f32x2){ wdn_g[2 * t + 1], wdn_g[2 * t] };
    }
    const float a     = __expf(alpha[c]);
    const float inv_a = 1.0f / (a + 1e-9f);
    const float ka    = a * INV_2PI;    // v_sin_f32 takes revolutions
    const f32x2 ka2   = (f32x2){ ka, ka };
    const f32x2 inva2 = (f32x2){ inv_a, inv_a };

    // ---- upsample, packed: A[p] = (yv[2p], yv[2p-1]), p=1..8 ----
    f32x2 A[14];
#pragma unroll
    for (int p = 1; p <= 8; ++p)
        A[p] = (f32x2){ 0.0f, 0.0f };
#pragma unroll
    for (int u = 3; u <= 15; ++u) {
        const f32x2 su = (f32x2){ xr[u], xr[u] };
#pragma unroll
        for (int t = 0; t < 6; ++t) {
            const int p = u - 7 + t;
            if (p >= 1 && p <= 8)
                A[p] = __builtin_elementwise_fma(cpair[t], su, A[p]);
        }
    }

    // ---- snake, packed (scalar v_sin per half) ----
#pragma unroll
    for (int p = 1; p <= 8; ++p) {
        const f32x2 arg = A[p] * ka2;
        const f32x2 s   = (f32x2){ __builtin_amdgcn_sinf(arg.x),
                                   __builtin_amdgcn_sinf(arg.y) };
        A[p] = __builtin_elementwise_fma(s * s, inva2, A[p]);
    }

    // ---- left edge: ypad[m<0] = y[0]  (yv[1..5] = yv[6] when N==0) ----
    if (N == 0) {
        const float v = A[3].x;           // snaked yv[6]
        A[1] = (f32x2){ v, v };
        A[2] = (f32x2){ v, v };
        A[3].y = v;
    }

    // ---- lane-parallel halo y (lane v<11 real, others harmless) ----
    float yh = 0.0f;
#pragma unroll
    for (int j = 0; j < 6; ++j) {
        const float cj = par ? cpair[5 - j].y : cpair[5 - j].x;
        yh = fmaf(cj, xt[j], yh);
    }
    {
        const float s = __builtin_amdgcn_sinf(ka * yh);
        yh = fmaf(s * s, inv_a, yh);
    }

    // ---- halo pairs A[9..13]: shfl_down(A[1..5]); lane 63 via readlane ----
    const bool is63 = (lane == 63);
#pragma unroll
    for (int p = 1; p <= 5; ++p) {
        const float dx = __shfl_down(A[p].x, 1, 64);
        const float dy = __shfl_down(A[p].y, 1, 64);
        const float gx = __int_as_float(
            __builtin_amdgcn_readlane(__float_as_int(yh), 2 * p));
        const float gy = __int_as_float(
            __builtin_amdgcn_readlane(__float_as_int(yh), 2 * p - 1));
        A[8 + p] = (f32x2){ is63 ? gx : dx, is63 ? gy : dy };
    }

    // ---- right edge: ypad[m>16383] = y[16383]  (h[6..10] = h[5]) ----
    if (N == T_LEN - OPT) {
        const float h5 = A[11].y;
        A[11] = (f32x2){ h5, h5 };
        A[12] = (f32x2){ h5, h5 };
        A[13] = (f32x2){ h5, h5 };
    }

    // ---- downsample, packed: o_r = sum_j dpair[j] (.) A[r+j+1] ----
    float o[OPT];
#pragma unroll
    for (int r = 0; r < OPT; ++r) {
        f32x2 P = dpair[0] * A[r + 1];
#pragma unroll
        for (int j = 1; j < 6; ++j)
            P = __builtin_elementwise_fma(dpair[j], A[r + j + 1], P);
        o[r] = P.x + P.y;
    }

    *reinterpret_cast<float4*>(orow + N)     = make_float4(o[0], o[1], o[2], o[3]);
    *reinterpret_cast<float4*>(orow + N + 4) = make_float4(o[4], o[5], o[6], o[7]);
}

extern "C" void kernel_launch(void* const* d_in, const int* in_sizes, int n_in,
                              void* d_out, int out_size, void* d_ws, size_t ws_size,
                              hipStream_t stream)
{
    const float* x     = (const float*)d_in[0];
    const float* alpha = (const float*)d_in[1];
    const float* wup   = (const float*)d_in[2];
    const float* wdn   = (const float*)d_in[3];
    float*       out   = (float*)d_out;

    const int B_N  = out_size / (C_N * T_LEN);   // 8
    const int grid = B_N * C_N * NCHUNK;         // 16384

    act1d_fused<<<grid, BLOCK, 0, stream>>>(x, alpha, wup, wdn, out);
}